// Round 1
// baseline (559.772 us; speedup 1.0000x reference)
//
#include <hip/hip_runtime.h>
#include <math.h>

// SfmPool: softmax-weighted 3x3 stride-2 SAME pooling, NHWC f32.
// Input (32,128,128,192) -> Output (32,64,64,192).
//
// Round 4: software-pipelined loads. The former `step` is split into
// issue_loads (global->reg batch for iteration p+2) and compute_step
// (consume batch p). Each 26-load batch now has one full compute phase
// (x3 resident waves) between issue and waitcnt, instead of the previous
// issue->wait->compute serialization. Row addressing moved from 13 VGPR
// offsets to 13 uniform (SGPR) row-base pointers + one VGPR voff, paying
// for the second register buffer. Math (emit1, masks, parity rings) is
// identical to the verified round-3 kernel.

#define B  32
#define H  128
#define W  128
#define C  192
#define OH 64
#define OW 64
#define S  4
#define G  (OH / S)        // 16 oh-groups
#define NR (2 * S + 5)     // 13 strip rows
#define NW (S + 2)         // 6 window-rows
#define NCR (2 * S + 1)    // 9 center rows
#define CB (C * 4)         // 768 B per column step
#define ROWB (W * C * 4)   // 98304 B per input row
#define OSTRIDE (OW * C * 4)  // 49152 B per output row
#define NEG_INF (-__builtin_inff())

// One output. Mm1/M0/Mp1: window maxes of col-windows ow-1, ow, ow+1 (a =
// window-row oh-1+a). c0/c1/c2: input cols 2ow..2ow+2, rows 2oh..2oh+2 (di).
// All masks are compile-time template bools.
template <bool WAL, bool WAH, bool WQL, bool WQH>
__device__ __forceinline__ float emit1(const float* Mm1, const float* M0,
                                       const float* Mp1, const float* c0,
                                       const float* c1, const float* c2) {
    const float Z00 = (WAL && WQL) ? Mm1[0] : 0.f;
    const float Z01 = WAL ? M0[0] : 0.f;
    const float Z02 = (WAL && WQH) ? Mp1[0] : 0.f;
    const float Z10 = WQL ? Mm1[1] : 0.f;
    const float Z11 = M0[1];
    const float Z12 = WQH ? Mp1[1] : 0.f;
    const float Z20 = (WAH && WQL) ? Mm1[2] : 0.f;
    const float Z21 = WAH ? M0[2] : 0.f;
    const float Z22 = (WAH && WQH) ? Mp1[2] : 0.f;

    const float T0a0 = Z00 + Z01, T0a1 = Z10 + Z11, T0a2 = Z20 + Z21;
    const float T2a0 = Z01 + Z02, T2a1 = Z11 + Z12, T2a2 = Z21 + Z22;

    const float mv00 = T0a0 + T0a1;
    const float mv01 = Z01 + Z11;
    const float mv02 = T2a0 + T2a1;
    const float mv10 = T0a1;
    const float mv11 = Z11;
    const float mv12 = T2a1;
    const float mv20 = T0a1 + T0a2;
    const float mv21 = Z11 + Z21;
    const float mv22 = T2a1 + T2a2;

    float num = 0.f, den = 0.f, v, e;
    v = c0[0]; e = __expf(v - mv00); num = fmaf(v, e, num); den += e;
    v = c1[0]; e = __expf(v - mv01); num = fmaf(v, e, num); den += e;
    v = c0[1]; e = __expf(v - mv10); num = fmaf(v, e, num); den += e;
    v = c1[1]; e = __expf(v - mv11); num = fmaf(v, e, num); den += e;
    if (WQH) {
        v = c2[0]; e = __expf(v - mv02); num = fmaf(v, e, num); den += e;
        v = c2[1]; e = __expf(v - mv12); num = fmaf(v, e, num); den += e;
    }
    if (WAH) {
        v = c0[2]; e = __expf(v - mv20); num = fmaf(v, e, num); den += e;
        v = c1[2]; e = __expf(v - mv21); num = fmaf(v, e, num); den += e;
        if (WQH) {
            v = c2[2]; e = __expf(v - mv22); num = fmaf(v, e, num); den += e;
        }
    }
    return __fdividef(num, den);
}

// Issue global->reg loads for one 2-column batch. rp[] are uniform
// (blockIdx-derived) row base pointers -> SGPR base + VGPR voff addressing.
// Rows outside [RLO,RHI] are not loaded (compute substitutes NEG_INF).
template <int RLO, int RHI, bool LV, bool LR>
__device__ __forceinline__ void issue_loads(const char* const rp[NR],
                                            unsigned voff, float vl[NR],
                                            float vr[NR]) {
#pragma unroll
    for (int r = 0; r < NR; ++r) {
        if (r >= RLO && r <= RHI) {
            if (LV) vl[r] = *(const float*)(rp[r] + voff);
            if (LR) vr[r] = *(const float*)(rp[r] + voff + CB);
        }
    }
}

// Consume one batch (iteration p): cols 2p+1 (vl), 2p+2 (vr); emit ow=p-1.
// PAR = p&1 selects ring slots (compile-time). VL/VR: whether the buffer
// holds valid data (else NEG_INF padding, e.g. cols -1 / 128).
template <int PAR, int RLO, int RHI, bool VL, bool VR, bool WALO, bool WAHI,
          bool EMIT, bool WQL, bool WQH>
__device__ __forceinline__ void compute_step(const float vlr[NR],
                                             const float vrr[NR], float vmP[NW],
                                             float Mh[2][NW], float CL[2][NCR],
                                             float CR[2][NCR],
                                             char* __restrict__ ob,
                                             unsigned& ooff) {
    float vl[NR], vr[NR];
#pragma unroll
    for (int r = 0; r < NR; ++r) {
        const bool rv = (r >= RLO && r <= RHI);
        vl[r] = (VL && rv) ? vlr[r] : NEG_INF;
        vr[r] = (VR && rv) ? vrr[r] : NEG_INF;
    }
    float vmL[NW], vmR[NW], Mp[NW];
#pragma unroll
    for (int w = 0; w < NW; ++w) {
        vmL[w] = fmaxf(fmaxf(vl[2 * w], vl[2 * w + 1]), vl[2 * w + 2]);
        vmR[w] = fmaxf(fmaxf(vr[2 * w], vr[2 * w + 1]), vr[2 * w + 2]);
        Mp[w] = fmaxf(fmaxf(vmP[w], vmL[w]), vmR[w]);
    }
    if (EMIT) {
        // slot s -> oh = oh0+s; window-rows w=s..s+2; center rows k=2s..2s+2.
        {
            float o = emit1<WALO, true, WQL, WQH>(
                &Mh[PAR][0], &Mh[PAR ^ 1][0], &Mp[0],
                &CR[PAR][0], &CL[PAR ^ 1][0], &CR[PAR ^ 1][0]);
            *(float*)(ob + ooff + 0 * OSTRIDE) = o;
        }
        {
            float o = emit1<true, true, WQL, WQH>(
                &Mh[PAR][1], &Mh[PAR ^ 1][1], &Mp[1],
                &CR[PAR][2], &CL[PAR ^ 1][2], &CR[PAR ^ 1][2]);
            *(float*)(ob + ooff + 1 * OSTRIDE) = o;
        }
        {
            float o = emit1<true, true, WQL, WQH>(
                &Mh[PAR][2], &Mh[PAR ^ 1][2], &Mp[2],
                &CR[PAR][4], &CL[PAR ^ 1][4], &CR[PAR ^ 1][4]);
            *(float*)(ob + ooff + 2 * OSTRIDE) = o;
        }
        {
            float o = emit1<true, WAHI, WQL, WQH>(
                &Mh[PAR][3], &Mh[PAR ^ 1][3], &Mp[3],
                &CR[PAR][6], &CL[PAR ^ 1][6], &CR[PAR ^ 1][6]);
            *(float*)(ob + ooff + 3 * OSTRIDE) = o;
        }
        ooff += CB;
    }
    // ring update (after emit)
#pragma unroll
    for (int w = 0; w < NW; ++w) {
        Mh[PAR][w] = Mp[w];
        vmP[w] = vmR[w];
    }
#pragma unroll
    for (int k = 0; k < NCR; ++k) {
        CL[PAR][k] = vl[k + 2];
        CR[PAR][k] = vr[k + 2];
    }
}

template <int RLO, int RHI, bool WALO, bool WAHI, bool FIRST>
__device__ __forceinline__ void sweep(const char* __restrict__ sb,
                                      char* __restrict__ ob, int oh0, int c) {
    constexpr int start = FIRST ? 0 : OW / 2;
    const int j0 = FIRST ? 0 : (2 * start - 2);  // first loaded column

    // Uniform row base pointers (SGPRs): clamped rows 2*oh0-2 .. 2*oh0+10.
    const char* rp[NR];
#pragma unroll
    for (int r = 0; r < NR; ++r) {
        int i = 2 * oh0 - 2 + r;
        if (i < 0) i = 0;
        if (i > H - 1) i = H - 1;
        rp[r] = sb + (size_t)i * ROWB;
    }
    unsigned voff = (unsigned)((j0 * C + c) * 4);  // per-thread column offset
    unsigned ooff = (unsigned)(((oh0 * OW + start) * C + c) * 4);

    float vmP[NW], Mh[2][NW], CL[2][NCR], CR[2][NCR];
    float v0[NR], vlA[NR], vrA[NR], vlB[NR], vrB[NR];

    // ---- issue warm column + first two pipelined batches ----
    issue_loads<RLO, RHI, true, false>(rp, voff, v0, v0);
    voff += CB;
    if (FIRST) {
        issue_loads<RLO, RHI, true, true>(rp, voff, vlA, vrA); voff += 2 * CB;  // p0: cols 1,2
        issue_loads<RLO, RHI, true, true>(rp, voff, vlB, vrB); voff += 2 * CB;  // p1: cols 3,4
    } else {
        issue_loads<RLO, RHI, true, true>(rp, voff, vlB, vrB); voff += 2 * CB;  // p31: cols 63,64
        issue_loads<RLO, RHI, true, true>(rp, voff, vlA, vrA); voff += 2 * CB;  // p32: cols 65,66
    }

    // ---- consume warm column (waits only on the oldest 13 loads) ----
    float v0m[NR];
#pragma unroll
    for (int r = 0; r < NR; ++r)
        v0m[r] = (r >= RLO && r <= RHI) ? v0[r] : NEG_INF;

    if (FIRST) {
        // acts as iter p=-1 (PAR=1): vl(col -1) skipped, vr = col 0.
#pragma unroll
        for (int w = 0; w < NW; ++w) {
            float vm0 = fmaxf(fmaxf(v0m[2 * w], v0m[2 * w + 1]), v0m[2 * w + 2]);
            Mh[1][w] = vm0;   // M_{-1} (consumed only under WQL=false mask)
            vmP[w] = vm0;     // vm of col 0
        }
#pragma unroll
        for (int k = 0; k < NCR; ++k) {
            CL[1][k] = NEG_INF;        // col -1, never consumed
            CR[1][k] = v0m[k + 2];     // col 0 centers
        }
    } else {
        // pre-warm: col 62 -> vmP
#pragma unroll
        for (int w = 0; w < NW; ++w)
            vmP[w] = fmaxf(fmaxf(v0m[2 * w], v0m[2 * w + 1]), v0m[2 * w + 2]);
    }

    if (FIRST) {
        // p0 (PAR=0, no emit); then refill A with p2
        compute_step<0, RLO, RHI, true, true, WALO, WAHI, false, true, true>(
            vlA, vrA, vmP, Mh, CL, CR, ob, ooff);
        issue_loads<RLO, RHI, true, true>(rp, voff, vlA, vrA); voff += 2 * CB;  // p2
        // p1 (PAR=1, emit ow=0, left col-window masked); refill B with p3
        compute_step<1, RLO, RHI, true, true, WALO, WAHI, true, false, true>(
            vlB, vrB, vmP, Mh, CL, CR, ob, ooff);
        issue_loads<RLO, RHI, true, true>(rp, voff, vlB, vrB); voff += 2 * CB;  // p3
#pragma unroll 1
        for (int t = 0; t < 14; ++t) {  // computes p=2..29, loads p=4..31
            compute_step<0, RLO, RHI, true, true, WALO, WAHI, true, true, true>(
                vlA, vrA, vmP, Mh, CL, CR, ob, ooff);
            issue_loads<RLO, RHI, true, true>(rp, voff, vlA, vrA); voff += 2 * CB;
            compute_step<1, RLO, RHI, true, true, WALO, WAHI, true, true, true>(
                vlB, vrB, vmP, Mh, CL, CR, ob, ooff);
            issue_loads<RLO, RHI, true, true>(rp, voff, vlB, vrB); voff += 2 * CB;
        }
        // p30 (A); load final batch p32 into A
        compute_step<0, RLO, RHI, true, true, WALO, WAHI, true, true, true>(
            vlA, vrA, vmP, Mh, CL, CR, ob, ooff);
        issue_loads<RLO, RHI, true, true>(rp, voff, vlA, vrA); voff += 2 * CB;  // p32
        // p31 (B)
        compute_step<1, RLO, RHI, true, true, WALO, WAHI, true, true, true>(
            vlB, vrB, vmP, Mh, CL, CR, ob, ooff);
        // p32 (A): emit ow=31
        compute_step<0, RLO, RHI, true, true, WALO, WAHI, true, true, true>(
            vlA, vrA, vmP, Mh, CL, CR, ob, ooff);
    } else {
        // p31 (B, no emit); refill B with p33
        compute_step<1, RLO, RHI, true, true, WALO, WAHI, false, true, true>(
            vlB, vrB, vmP, Mh, CL, CR, ob, ooff);
        issue_loads<RLO, RHI, true, true>(rp, voff, vlB, vrB); voff += 2 * CB;  // p33
        // p32 (A, no emit); refill A with p34
        compute_step<0, RLO, RHI, true, true, WALO, WAHI, false, true, true>(
            vlA, vrA, vmP, Mh, CL, CR, ob, ooff);
        issue_loads<RLO, RHI, true, true>(rp, voff, vlA, vrA); voff += 2 * CB;  // p34
#pragma unroll 1
        for (int t = 0; t < 14; ++t) {  // computes p=33..60, loads p=35..62
            compute_step<1, RLO, RHI, true, true, WALO, WAHI, true, true, true>(
                vlB, vrB, vmP, Mh, CL, CR, ob, ooff);
            issue_loads<RLO, RHI, true, true>(rp, voff, vlB, vrB); voff += 2 * CB;
            compute_step<0, RLO, RHI, true, true, WALO, WAHI, true, true, true>(
                vlA, vrA, vmP, Mh, CL, CR, ob, ooff);
            issue_loads<RLO, RHI, true, true>(rp, voff, vlA, vrA); voff += 2 * CB;
        }
        // p61 (B); load p63 into B (vl = col 127 only, vr is the pad)
        compute_step<1, RLO, RHI, true, true, WALO, WAHI, true, true, true>(
            vlB, vrB, vmP, Mh, CL, CR, ob, ooff);
        issue_loads<RLO, RHI, true, false>(rp, voff, vlB, vrB);  // p63
        // p62 (A)
        compute_step<0, RLO, RHI, true, true, WALO, WAHI, true, true, true>(
            vlA, vrA, vmP, Mh, CL, CR, ob, ooff);
        // p63 (B): vr padded NEG_INF; emit ow=62
        compute_step<1, RLO, RHI, true, false, WALO, WAHI, true, true, true>(
            vlB, vrB, vmP, Mh, CL, CR, ob, ooff);
        // p64 (A): emit-only, ow=63 (right col-window masked)
        compute_step<0, RLO, RHI, false, false, WALO, WAHI, true, true, false>(
            vlA, vrA, vmP, Mh, CL, CR, ob, ooff);
    }
}

__global__ __launch_bounds__(192, 3) void sfmpool_s4_kernel(
    const float* __restrict__ in, float* __restrict__ out) {
    const int c = threadIdx.x;            // 0..191 (channel)
    const int half = blockIdx.x;          // 0..1 (ow half)
    const int g = blockIdx.y;             // 0..15 (oh group)
    const int b = blockIdx.z;             // 0..31
    const char* sb = (const char*)(in + (size_t)b * (H * W * C));
    char* ob = (char*)(out + (size_t)b * (OH * OW * C));
    const int oh0 = g * S;

    if (g == 0) {
        if (half == 0) sweep<2, 12, false, true, true>(sb, ob, oh0, c);
        else           sweep<2, 12, false, true, false>(sb, ob, oh0, c);
    } else if (g == G - 1) {
        if (half == 0) sweep<0, 9, true, false, true>(sb, ob, oh0, c);
        else           sweep<0, 9, true, false, false>(sb, ob, oh0, c);
    } else {
        if (half == 0) sweep<0, 12, true, true, true>(sb, ob, oh0, c);
        else           sweep<0, 12, true, true, false>(sb, ob, oh0, c);
    }
}

extern "C" void kernel_launch(void* const* d_in, const int* in_sizes, int n_in,
                              void* d_out, int out_size, void* d_ws, size_t ws_size,
                              hipStream_t stream) {
    const float* in = (const float*)d_in[0];
    float* out = (float*)d_out;
    dim3 grid(2, G, B);   // (ow-half, oh-group, batch) = 1024 blocks
    dim3 block(C);        // 192 threads = 3 waves (lane = channel)
    sfmpool_s4_kernel<<<grid, block, 0, stream>>>(in, out);
}